// Round 8
// baseline (4478.252 us; speedup 1.0000x reference)
//
#include <hip/hip_runtime.h>
#include <hip/hip_bf16.h>

#define N_NODES 100000
#define N_EDGES 1600000
#define IN_F    128
#define N_HID   512
#define N_CLS   64
#define BN_EPS  1e-5f
#define NB_GRAM 391      // ceil(100000/256)
#define SCAN_PAD 114688  // 7 * 16384
#define NBUCK   782      // ceil(100000/128) node buckets (dst>>7)
#define BIN_BLKS 128
#define EPB     12500    // edges per binning block: 128*12500 = 1.6M exactly

typedef __attribute__((ext_vector_type(8))) short short8;
typedef __attribute__((ext_vector_type(4))) float floatx4;

__device__ __forceinline__ short f2bf(float x) {
    union { float f; unsigned u; } t; t.f = x;
    unsigned r = (t.u + 0x7fffu + ((t.u >> 16) & 1u)) >> 16;
    return (short)r;
}
__device__ __forceinline__ float bf2f(short s) {
    union { float f; unsigned u; } t; t.u = ((unsigned)(unsigned short)s) << 16;
    return t.f;
}

// ---------------- feat fp32 -> bf16 ----------------
__global__ void cvtf_k(const float4* __restrict__ f, short* __restrict__ o) {
    int i = blockIdx.x * 256 + threadIdx.x;   // 3.2M threads, exact
    float4 v = f[i];
    short4 s;
    s.x = f2bf(v.x); s.y = f2bf(v.y); s.z = f2bf(v.z); s.w = f2bf(v.w);
    *(short4*)(o + (size_t)i * 4) = s;
}

// ---------------- atomic-free bucketed CSR build ----------------
// Round-7 lesson: per-edge device-scope atomics cost 64B-line RMW each
// (WRITE_SIZE == 64B * E regardless of payload). All per-edge atomics below
// are LDS-only; global writes are dense.
__global__ void __launch_bounds__(256) binhist_k(const int* __restrict__ dst,
                                                 int* __restrict__ Cmat) {
    __shared__ int hist[NBUCK];
    int tid = threadIdx.x, b = blockIdx.x;
    for (int k = tid; k < NBUCK; k += 256) hist[k] = 0;
    __syncthreads();
    int base = b * EPB;
    for (int i = tid; i < EPB; i += 256)
        atomicAdd(&hist[dst[base + i] >> 7], 1);
    __syncthreads();
    for (int k = tid; k < NBUCK; k += 256) Cmat[k * BIN_BLKS + b] = hist[k];
}

// 1024 threads, 16 elems/thread, shfl-scan over the flat [bucket][block]
// count matrix (100,096 used, zero-padded to SCAN_PAD). In-place -> exclusive
// prefix = write cursors; indptr is scratch (unused downstream).
__global__ void __launch_bounds__(1024) scan_k(int* __restrict__ counts, int* __restrict__ indptr) {
    __shared__ int wsum[16];
    __shared__ int s_carry;
    int tid = threadIdx.x;
    int lane = tid & 63, wid = tid >> 6;
    if (tid == 0) { s_carry = 0; indptr[0] = 0; }
    __syncthreads();
    for (int base = 0; base < SCAN_PAD; base += 16384) {
        int idx = base + tid * 16;
        int vv[16];
#pragma unroll
        for (int u = 0; u < 4; u++) {
            int4 v = *(const int4*)(counts + idx + u * 4);
            vv[u * 4 + 0] = v.x; vv[u * 4 + 1] = v.y;
            vv[u * 4 + 2] = v.z; vv[u * 4 + 3] = v.w;
        }
        int s = 0;
#pragma unroll
        for (int u = 0; u < 16; u++) s += vv[u];
        int sc = s;
#pragma unroll
        for (int off = 1; off < 64; off <<= 1) {
            int t = __shfl_up(sc, off, 64);
            if (lane >= off) sc += t;
        }
        if (lane == 63) wsum[wid] = sc;
        __syncthreads();
        if (wid == 0) {
            int wv = (lane < 16) ? wsum[lane] : 0;
#pragma unroll
            for (int off = 1; off < 16; off <<= 1) {
                int t = __shfl_up(wv, off, 64);
                if (lane >= off) wv += t;
            }
            if (lane < 16) wsum[lane] = wv;
        }
        __syncthreads();
        int carry = s_carry;
        int wave_excl = (wid == 0) ? 0 : wsum[wid - 1];
        int run = carry + wave_excl + (sc - s);
#pragma unroll
        for (int u = 0; u < 16; u++) {
            int t = vv[u];
            vv[u] = run;
            run += t;
            indptr[idx + u + 1] = run;
        }
#pragma unroll
        for (int u = 0; u < 4; u++) {
            int4 o = {vv[u * 4 + 0], vv[u * 4 + 1], vv[u * 4 + 2], vv[u * 4 + 3]};
            *(int4*)(counts + idx + u * 4) = o;
        }
        __syncthreads();
        if (tid == 0) s_carry = carry + wsum[15];
        __syncthreads();
    }
}

// place edges bucket-grouped; position via LDS cursor (stable per block-range)
// record: x = (dst&127)<<17 | src  (24 bits), y = norm fp32 bits
__global__ void __launch_bounds__(256) bscatter_k(const int* __restrict__ src,
                                                  const int* __restrict__ dst,
                                                  const float* __restrict__ norm,
                                                  const int* __restrict__ Cmat,
                                                  int2* __restrict__ ebuf) {
    __shared__ int cur[NBUCK];
    int tid = threadIdx.x, b = blockIdx.x;
    for (int k = tid; k < NBUCK; k += 256) cur[k] = Cmat[k * BIN_BLKS + b];
    __syncthreads();
    int base = b * EPB;
    for (int i = tid; i < EPB; i += 256) {
        int e = base + i;
        int d = dst[e];
        int pos = atomicAdd(&cur[d >> 7], 1);
        int2 r;
        r.x = ((d & 127) << 17) | src[e];
        r.y = __float_as_int(norm[e]);
        ebuf[pos] = r;
    }
}

// ---------------- hop: one 128-node bucket per block, LDS fp32 accumulator --
__global__ void __launch_bounds__(256) hopb2_k(const short* __restrict__ fin,
                                               short* __restrict__ fout,
                                               const int* __restrict__ Cmat,
                                               const int2* __restrict__ ebuf) {
    __shared__ float acc[128][128];   // 64 KB -> 2 blocks/CU
    int tid = threadIdx.x;
    int w = tid >> 6, l = tid & 63;
    int bkt = blockIdx.x;
    float4* az = (float4*)acc;
    for (int i = tid; i < 128 * 32; i += 256) az[i] = (float4){0.f, 0.f, 0.f, 0.f};
    int beg = Cmat[bkt * BIN_BLKS];
    int end = (bkt < NBUCK - 1) ? Cmat[(bkt + 1) * BIN_BLKS] : N_EDGES;
    __syncthreads();
    // contiguous per-wave edge range; 4 edges per iteration (wave-uniform guards)
    int cnt = end - beg;
    int per = (cnt + 3) >> 2;
    int ws_ = beg + w * per;
    int we_ = min(ws_ + per, end);
    int j4 = l & 3;
    for (int e = ws_; e < we_; e += 4) {
        int ei = e + j4; if (ei >= we_) ei = we_ - 1;
        int2 rec = ebuf[ei];
#pragma unroll
        for (int j = 0; j < 4; j++) {
            if (e + j < we_) {
                int rx = __shfl(rec.x, j, 4);
                float wt = __int_as_float(__shfl(rec.y, j, 4));
                int s  = rx & 0x1FFFF;
                int dl = rx >> 17;
                short2 sv = *(const short2*)(fin + (size_t)s * 128 + 2 * l);
                atomicAdd(&acc[dl][2 * l],     bf2f(sv.x) * wt);
                atomicAdd(&acc[dl][2 * l + 1], bf2f(sv.y) * wt);
            }
        }
    }
    __syncthreads();
    int node0 = bkt * 128;
    for (int i = tid; i < 128 * 16; i += 256) {
        int r = i >> 4, g = i & 15;
        int node = node0 + r;
        if (node < N_NODES) {
            short sv[8];
#pragma unroll
            for (int d = 0; d < 8; d++) sv[d] = f2bf(acc[r][g * 8 + d]);
            *(int4*)(fout + (size_t)node * 128 + g * 8) = *(int4*)sv;
        }
    }
}

// ---------------- MFMA Gram: Gpart[b] = ftb_chunk^T @ ftb_chunk ----------------
__global__ void __launch_bounds__(256) gram_k(const short* __restrict__ ftb,
                                              float* __restrict__ Gpart,
                                              float* __restrict__ colsum) {
    __shared__ int  sInt[128 * 17];
    __shared__ float scol[128];
    int tid = threadIdx.x;
    int w   = tid >> 6;
    int l   = tid & 63;
    int q   = l >> 4;
    int r16 = l & 15;
    int i0  = (w >> 1) * 64;
    int j0  = (w & 1) * 64;
    int row0 = blockIdx.x * 256;
    short* sS = (short*)sInt;

    if (tid < 128) scol[tid] = 0.f;

    floatx4 acc[4][4];
#pragma unroll
    for (int a = 0; a < 4; a++)
#pragma unroll
        for (int b = 0; b < 4; b++) acc[a][b] = (floatx4){0.f, 0.f, 0.f, 0.f};
    float colacc[8] = {0.f,0.f,0.f,0.f,0.f,0.f,0.f,0.f};
    int g = tid & 15;

    for (int st = 0; st < 8; st++) {
        __syncthreads();
#pragma unroll
        for (int uu = 0; uu < 2; uu++) {
            int r = (tid >> 4) + uu * 16;
            int gr = row0 + st * 32 + r;
            short v[8];
            if (gr < N_NODES) {
                *(int4*)v = *(const int4*)(ftb + (size_t)gr * 128 + g * 8);
            } else {
#pragma unroll
                for (int d = 0; d < 8; d++) v[d] = 0;
            }
#pragma unroll
            for (int d = 0; d < 8; d++) {
                sS[(g * 8 + d) * 34 + r] = v[d];
                colacc[d] += bf2f(v[d]);
            }
        }
        __syncthreads();
        short8 af[4], bf[4];
#pragma unroll
        for (int ti = 0; ti < 4; ti++) {
            union { int i[4]; short8 s; } u;
            const int* base = &sInt[(i0 + ti * 16 + r16) * 17 + q * 4];
            u.i[0] = base[0]; u.i[1] = base[1]; u.i[2] = base[2]; u.i[3] = base[3];
            af[ti] = u.s;
        }
#pragma unroll
        for (int tj = 0; tj < 4; tj++) {
            union { int i[4]; short8 s; } u;
            const int* base = &sInt[(j0 + tj * 16 + r16) * 17 + q * 4];
            u.i[0] = base[0]; u.i[1] = base[1]; u.i[2] = base[2]; u.i[3] = base[3];
            bf[tj] = u.s;
        }
#pragma unroll
        for (int ti = 0; ti < 4; ti++)
#pragma unroll
            for (int tj = 0; tj < 4; tj++)
                acc[ti][tj] = __builtin_amdgcn_mfma_f32_16x16x32_bf16(af[ti], bf[tj], acc[ti][tj], 0, 0, 0);
    }

    float* gp = Gpart + (size_t)blockIdx.x * 16384;
#pragma unroll
    for (int ti = 0; ti < 4; ti++) {
        int gi = i0 + ti * 16 + q * 4;
#pragma unroll
        for (int tj = 0; tj < 4; tj++) {
            int gj = j0 + tj * 16 + r16;
#pragma unroll
            for (int i2 = 0; i2 < 4; i2++)
                gp[(gi + i2) * 128 + gj] = acc[ti][tj][i2];
        }
    }
    __syncthreads();
#pragma unroll
    for (int d = 0; d < 8; d++) atomicAdd(&scol[g * 8 + d], colacc[d]);
    __syncthreads();
    if (tid < 128) atomicAdd(&colsum[tid], scol[tid]);
}

__global__ void __launch_bounds__(256) reduce_k(const float* __restrict__ Gpart,
                                                float* __restrict__ G) {
    int idx = blockIdx.x * 256 + threadIdx.x;
    float s = 0.f;
    for (int b = 0; b < NB_GRAM; b++) s += Gpart[(size_t)b * 16384 + idx];
    G[idx] = s;
}

// ---------------- BN stats from Gram: one block per hidden unit ----------------
__global__ void __launch_bounds__(128) bnstat_k(const float* __restrict__ G,
                                                const float* __restrict__ colsum,
                                                const float* __restrict__ W1,
                                                const float* __restrict__ b1,
                                                const float* __restrict__ gamma,
                                                const float* __restrict__ beta,
                                                float* __restrict__ scale,
                                                float* __restrict__ shift) {
    __shared__ float sw[128];
    __shared__ float red[4];
    int j = blockIdx.x;
    int l = threadIdx.x;
    float wl = W1[(size_t)j * IN_F + l];
    sw[l] = wl;
    __syncthreads();
    float t = 0.f;
#pragma unroll 8
    for (int k = 0; k < 128; k++) t += sw[k] * G[k * 128 + l];
    float q = wl * t;
    float m = colsum[l] * wl;
#pragma unroll
    for (int off = 32; off >= 1; off >>= 1) {
        q += __shfl_xor(q, off, 64);
        m += __shfl_xor(m, off, 64);
    }
    if ((l & 63) == 0) { red[(l >> 6) * 2] = q; red[(l >> 6) * 2 + 1] = m; }
    __syncthreads();
    if (l == 0) {
        float qq = red[0] + red[2];
        float mm = red[1] + red[3];
        const float invN = 1.f / (float)N_NODES;
        float mean_dot = mm * invN;
        float var = qq * invN - mean_dot * mean_dot;
        float inv = rsqrtf(var + BN_EPS);
        float s = gamma[j] * inv;
        scale[j] = s;
        shift[j] = beta[j] - (mean_dot + b1[j]) * s;
    }
}

// ---------------- weight bf16 pre-conversion ----------------
__global__ void cvtw_k(const float* __restrict__ w1, const float* __restrict__ w2,
                       short* __restrict__ w1b, short* __restrict__ w2b) {
    int i = blockIdx.x * 256 + threadIdx.x;
    if (i < N_HID * IN_F) w1b[i] = f2bf(w1[i]);
    if (i < N_CLS * N_HID) w2b[i] = f2bf(w2[i]);
}

// ---------------- fused fc1 -> BN -> ReLU -> fc2, MFMA ----------------
__global__ void __launch_bounds__(256) mlp_k(const short* __restrict__ ftb,
                                             const short* __restrict__ w1b,
                                             const float* __restrict__ b1,
                                             const float* __restrict__ scale,
                                             const float* __restrict__ shift,
                                             const short* __restrict__ w2b,
                                             const float* __restrict__ b2,
                                             float* __restrict__ out) {
    __shared__ short sA[128][136];
    __shared__ short sW1[64][136];
    __shared__ short sH[128][72];
    __shared__ short sW2[64][72];

    int tid = threadIdx.x;
    int w   = tid >> 6;
    int l   = tid & 63;
    int q   = l >> 4;
    int r16 = l & 15;
    int row0 = blockIdx.x * 128;

    for (int i = tid; i < 128 * 16; i += 256) {
        int r = i >> 4, g = i & 15;
        int gr = row0 + r;
        int4 v = {0, 0, 0, 0};
        if (gr < N_NODES) v = *(const int4*)(ftb + (size_t)gr * 128 + g * 8);
        *(int4*)&sA[r][g * 8] = v;
    }

    floatx4 oacc[2][4];
#pragma unroll
    for (int rt = 0; rt < 2; rt++)
#pragma unroll
        for (int tc = 0; tc < 4; tc++) oacc[rt][tc] = (floatx4){0.f, 0.f, 0.f, 0.f};

    for (int jc = 0; jc < 8; jc++) {
        int j0 = jc * 64;
        __syncthreads();
        for (int i = tid; i < 64 * 16; i += 256) {
            int j = i >> 4, k8 = i & 15;
            *(int4*)&sW1[j][k8 * 8] = *(const int4*)&w1b[(size_t)(j0 + j) * IN_F + k8 * 8];
        }
        for (int i = tid; i < 64 * 8; i += 256) {
            int c = i >> 3, k8 = i & 7;
            *(int4*)&sW2[c][k8 * 8] = *(const int4*)&w2b[(size_t)c * N_HID + j0 + k8 * 8];
        }
        __syncthreads();

        floatx4 hacc[2][4];
#pragma unroll
        for (int rt = 0; rt < 2; rt++)
#pragma unroll
            for (int tn = 0; tn < 4; tn++) hacc[rt][tn] = (floatx4){0.f, 0.f, 0.f, 0.f};
#pragma unroll
        for (int ks = 0; ks < 4; ks++) {
            short8 a0 = *(const short8*)&sA[w * 32 + r16][ks * 32 + q * 8];
            short8 a1 = *(const short8*)&sA[w * 32 + 16 + r16][ks * 32 + q * 8];
#pragma unroll
            for (int tn = 0; tn < 4; tn++) {
                short8 b = *(const short8*)&sW1[tn * 16 + r16][ks * 32 + q * 8];
                hacc[0][tn] = __builtin_amdgcn_mfma_f32_16x16x32_bf16(a0, b, hacc[0][tn], 0, 0, 0);
                hacc[1][tn] = __builtin_amdgcn_mfma_f32_16x16x32_bf16(a1, b, hacc[1][tn], 0, 0, 0);
            }
        }
#pragma unroll
        for (int tn = 0; tn < 4; tn++) {
            int col = j0 + tn * 16 + r16;
            float sc = scale[col], sh = shift[col], bb = b1[col];
#pragma unroll
            for (int rt = 0; rt < 2; rt++)
#pragma unroll
                for (int i = 0; i < 4; i++) {
                    float v = (hacc[rt][tn][i] + bb) * sc + sh;
                    sH[w * 32 + rt * 16 + q * 4 + i][tn * 16 + r16] = f2bf(fmaxf(v, 0.f));
                }
        }
        __syncthreads();
#pragma unroll
        for (int ks = 0; ks < 2; ks++) {
            short8 a0 = *(const short8*)&sH[w * 32 + r16][ks * 32 + q * 8];
            short8 a1 = *(const short8*)&sH[w * 32 + 16 + r16][ks * 32 + q * 8];
#pragma unroll
            for (int tc = 0; tc < 4; tc++) {
                short8 b = *(const short8*)&sW2[tc * 16 + r16][ks * 32 + q * 8];
                oacc[0][tc] = __builtin_amdgcn_mfma_f32_16x16x32_bf16(a0, b, oacc[0][tc], 0, 0, 0);
                oacc[1][tc] = __builtin_amdgcn_mfma_f32_16x16x32_bf16(a1, b, oacc[1][tc], 0, 0, 0);
            }
        }
    }

#pragma unroll
    for (int rt = 0; rt < 2; rt++)
#pragma unroll
        for (int tc = 0; tc < 4; tc++) {
            int col = tc * 16 + r16;
            float bb = b2[col];
#pragma unroll
            for (int i = 0; i < 4; i++) {
                int r = row0 + w * 32 + rt * 16 + q * 4 + i;
                if (r < N_NODES) out[(size_t)r * N_CLS + col] = oacc[rt][tc][i] + bb;
            }
        }
}

extern "C" void kernel_launch(void* const* d_in, const int* in_sizes, int n_in,
                              void* d_out, int out_size, void* d_ws, size_t ws_size,
                              hipStream_t stream) {
    const float* feat  = (const float*)d_in[0];
    const int*   src   = (const int*)d_in[1];
    const int*   dst   = (const int*)d_in[2];
    const float* gnorm = (const float*)d_in[3];
    const float* fc1w  = (const float*)d_in[4];
    const float* fc1b  = (const float*)d_in[5];
    const float* gam   = (const float*)d_in[6];
    const float* bet   = (const float*)d_in[7];
    const float* fc2w  = (const float*)d_in[8];
    const float* fc2b  = (const float*)d_in[9];
    float* out = (float*)d_out;

    char* ws = (char*)d_ws;
    const size_t FTB_BYTES = (size_t)N_NODES * IN_F * 2;   // 25.6 MB
    size_t off = 0;
    short* bufA   = (short*)(ws + off); off += FTB_BYTES;  // featb
    short* bufB   = (short*)(ws + off); off += FTB_BYTES;  // ft1b; ft3b aliases after hop2
    short* bufC   = (short*)(ws + off); off += FTB_BYTES;  // ft2b
    int*   indptr = (int*)(ws + off);   off += 460800;     // scan scratch
    int*   Cmat   = (int*)(ws + off);   off += SCAN_PAD * 4;   // [bucket][block] counts->prefix
    int2*  ebuf   = (int2*)(ws + off);  off += (size_t)N_EDGES * 8;  // bucket-grouped edges
    float* G      = (float*)(ws + off); off += 128 * 128 * 4;
    float* colsum = (float*)(ws + off); off += 512;
    float* scale  = (float*)(ws + off); off += 2048;
    float* shift  = (float*)(ws + off); off += 2048;
    short* w1b    = (short*)(ws + off); off += (size_t)N_HID * IN_F * 2;
    short* w2b    = (short*)(ws + off); off += (size_t)N_CLS * N_HID * 2;
    // Gpart: 391*64KB = 25,624,576 B — dedicated region (round-5 lesson).
    float* Gpart  = (float*)(ws + off); off += (size_t)NB_GRAM * 16384 * 4;
    short* featb  = bufA;
    short* ft1b   = bufB;
    short* ft2b   = bufC;
    short* ft3b   = bufB;               // reuse (ft1b dead after hop2)
    (void)ws_size; (void)in_sizes; (void)n_in; (void)out_size;

    hipMemsetAsync(Cmat, 0, SCAN_PAD * 4, stream);   // zeroes the scan padding tail
    hipMemsetAsync(colsum, 0, 512, stream);

    cvtf_k<<<12500, 256, 0, stream>>>((const float4*)feat, featb);
    cvtw_k<<<(N_HID * IN_F + 255) / 256, 256, 0, stream>>>(fc1w, fc2w, w1b, w2b);

    // atomic-free bucketed CSR build
    binhist_k<<<BIN_BLKS, 256, 0, stream>>>(dst, Cmat);
    scan_k<<<1, 1024, 0, stream>>>(Cmat, indptr);
    bscatter_k<<<BIN_BLKS, 256, 0, stream>>>(src, dst, gnorm, Cmat, ebuf);

    // 3 bf16 propagation hops (bucketed, LDS fp32 accumulation)
    hopb2_k<<<NBUCK, 256, 0, stream>>>(featb, ft1b, Cmat, ebuf);
    hopb2_k<<<NBUCK, 256, 0, stream>>>(ft1b, ft2b, Cmat, ebuf);
    hopb2_k<<<NBUCK, 256, 0, stream>>>(ft2b, ft3b, Cmat, ebuf);

    // BN stats via MFMA Gram (split-K partials + reduction)
    gram_k<<<NB_GRAM, 256, 0, stream>>>(ft3b, Gpart, colsum);
    reduce_k<<<64, 256, 0, stream>>>(Gpart, G);
    bnstat_k<<<N_HID, 128, 0, stream>>>(G, colsum, fc1w, fc1b, gam, bet, scale, shift);

    // fused MFMA MLP
    mlp_k<<<(N_NODES + 127) / 128, 256, 0, stream>>>(ft3b, w1b, fc1b, scale, shift,
                                                     w2b, fc2b, out);
}

// Round 9
// 546.776 us; speedup vs baseline: 8.1903x; 8.1903x over previous
//
#include <hip/hip_runtime.h>
#include <hip/hip_bf16.h>

#define N_NODES 100000
#define N_EDGES 1600000
#define IN_F    128
#define N_HID   512
#define N_CLS   64
#define BN_EPS  1e-5f
#define NB_GRAM 261      // ceil(100000/384) gram blocks (384 rows each)
#define SCAN_PAD 114688  // 7 * 16384
#define NBUCK   782      // ceil(100000/128) node buckets (dst>>7)
#define BIN_BLKS 128
#define EPB     12500    // edges per binning block: 128*12500 = 1.6M exactly

typedef __attribute__((ext_vector_type(8))) short short8;
typedef __attribute__((ext_vector_type(4))) float floatx4;

__device__ __forceinline__ short f2bf(float x) {
    union { float f; unsigned u; } t; t.f = x;
    unsigned r = (t.u + 0x7fffu + ((t.u >> 16) & 1u)) >> 16;
    return (short)r;
}
__device__ __forceinline__ float bf2f(short s) {
    union { float f; unsigned u; } t; t.u = ((unsigned)(unsigned short)s) << 16;
    return t.f;
}

// ---------------- feat fp32 -> bf16 ----------------
__global__ void cvtf_k(const float4* __restrict__ f, short* __restrict__ o) {
    int i = blockIdx.x * 256 + threadIdx.x;   // 3.2M threads, exact
    float4 v = f[i];
    short4 s;
    s.x = f2bf(v.x); s.y = f2bf(v.y); s.z = f2bf(v.z); s.w = f2bf(v.w);
    *(short4*)(o + (size_t)i * 4) = s;
}

// ---------------- atomic-free bucketed CSR build ----------------
// Round-7 lesson: per-edge device-scope atomics cost a 64B-line RMW each
// (WRITE_SIZE == 64B*E regardless of payload). Round-8 lesson: LDS-atomic
// scatter hops are latency-serialized (20x worse than gather). So: CSR build
// uses LDS atomics only + dense global writes; hops use gather-per-node.
__global__ void __launch_bounds__(256) binhist_k(const int* __restrict__ dst,
                                                 int* __restrict__ Cmat) {
    __shared__ int hist[NBUCK];
    int tid = threadIdx.x, b = blockIdx.x;
    for (int k = tid; k < NBUCK; k += 256) hist[k] = 0;
    __syncthreads();
    int base = b * EPB;
    for (int i = tid; i < EPB; i += 256)
        atomicAdd(&hist[dst[base + i] >> 7], 1);
    __syncthreads();
    for (int k = tid; k < NBUCK; k += 256) Cmat[k * BIN_BLKS + b] = hist[k];
}

// 1024 threads, 16 elems/thread, shfl-scan over the flat [bucket][block]
// count matrix (100,096 used, zero-padded to SCAN_PAD). In-place -> exclusive
// prefix = per-(bucket,block) cursors; 'scanout' is scratch.
__global__ void __launch_bounds__(1024) scan_k(int* __restrict__ counts, int* __restrict__ scanout) {
    __shared__ int wsum[16];
    __shared__ int s_carry;
    int tid = threadIdx.x;
    int lane = tid & 63, wid = tid >> 6;
    if (tid == 0) { s_carry = 0; scanout[0] = 0; }
    __syncthreads();
    for (int base = 0; base < SCAN_PAD; base += 16384) {
        int idx = base + tid * 16;
        int vv[16];
#pragma unroll
        for (int u = 0; u < 4; u++) {
            int4 v = *(const int4*)(counts + idx + u * 4);
            vv[u * 4 + 0] = v.x; vv[u * 4 + 1] = v.y;
            vv[u * 4 + 2] = v.z; vv[u * 4 + 3] = v.w;
        }
        int s = 0;
#pragma unroll
        for (int u = 0; u < 16; u++) s += vv[u];
        int sc = s;
#pragma unroll
        for (int off = 1; off < 64; off <<= 1) {
            int t = __shfl_up(sc, off, 64);
            if (lane >= off) sc += t;
        }
        if (lane == 63) wsum[wid] = sc;
        __syncthreads();
        if (wid == 0) {
            int wv = (lane < 16) ? wsum[lane] : 0;
#pragma unroll
            for (int off = 1; off < 16; off <<= 1) {
                int t = __shfl_up(wv, off, 64);
                if (lane >= off) wv += t;
            }
            if (lane < 16) wsum[lane] = wv;
        }
        __syncthreads();
        int carry = s_carry;
        int wave_excl = (wid == 0) ? 0 : wsum[wid - 1];
        int run = carry + wave_excl + (sc - s);
#pragma unroll
        for (int u = 0; u < 16; u++) {
            int t = vv[u];
            vv[u] = run;
            run += t;
            scanout[idx + u + 1] = run;
        }
#pragma unroll
        for (int u = 0; u < 4; u++) {
            int4 o = {vv[u * 4 + 0], vv[u * 4 + 1], vv[u * 4 + 2], vv[u * 4 + 3]};
            *(int4*)(counts + idx + u * 4) = o;
        }
        __syncthreads();
        if (tid == 0) s_carry = carry + wsum[15];
        __syncthreads();
    }
}

// place edges bucket-grouped; position via LDS cursor
// record: x = (dst&127)<<17 | src  (24 bits), y = norm fp32 bits
__global__ void __launch_bounds__(256) bscatter_k(const int* __restrict__ src,
                                                  const int* __restrict__ dst,
                                                  const float* __restrict__ norm,
                                                  const int* __restrict__ Cmat,
                                                  int2* __restrict__ ebuf) {
    __shared__ int cur[NBUCK];
    int tid = threadIdx.x, b = blockIdx.x;
    for (int k = tid; k < NBUCK; k += 256) cur[k] = Cmat[k * BIN_BLKS + b];
    __syncthreads();
    int base = b * EPB;
    for (int i = tid; i < EPB; i += 256) {
        int e = base + i;
        int d = dst[e];
        int pos = atomicAdd(&cur[d >> 7], 1);
        int2 r;
        r.x = ((d & 127) << 17) | src[e];
        r.y = __float_as_int(norm[e]);
        ebuf[pos] = r;
    }
}

// per-bucket counting sort by local node -> node-sorted packed edges + indptr
__global__ void __launch_bounds__(256) bsort_k(const int2* __restrict__ ebuf,
                                               const int* __restrict__ Cmat,
                                               unsigned* __restrict__ epack,
                                               int* __restrict__ indptr) {
    __shared__ int hist[128];
    __shared__ int cur[128];
    int tid = threadIdx.x;
    int bkt = blockIdx.x;
    if (tid < 128) hist[tid] = 0;
    int base = Cmat[bkt * BIN_BLKS];
    int end  = (bkt < NBUCK - 1) ? Cmat[(bkt + 1) * BIN_BLKS] : N_EDGES;
    __syncthreads();
    for (int e = base + tid; e < end; e += 256)
        atomicAdd(&hist[ebuf[e].x >> 17], 1);
    __syncthreads();
    int v = (tid < 128) ? hist[tid] : 0;
    // Hillis-Steele inclusive scan over 128 counts
    for (int off = 1; off < 128; off <<= 1) {
        int t = 0;
        if (tid < 128 && tid >= off) t = hist[tid - off];
        __syncthreads();
        if (tid < 128) hist[tid] += t;
        __syncthreads();
    }
    if (tid < 128) {
        int excl = base + hist[tid] - v;
        cur[tid] = excl;
        indptr[bkt * 128 + tid] = excl;   // covers nodes 0..100,095 incl. indptr[100000]
    }
    __syncthreads();
    for (int e = base + tid; e < end; e += 256) {
        int2 r = ebuf[e];
        int dl = r.x >> 17;
        int pos = atomicAdd(&cur[dl], 1);
        float nm = __int_as_float(r.y);
        unsigned qn = (unsigned)fminf(nm * 32768.f + 0.5f, 32767.f);
        epack[pos] = ((unsigned)(r.x & 0x1FFFF) << 15) | qn;
    }
}

// ---------------- bf16 propagation hop: one node per wave, 4 edges in flight ----
__global__ void __launch_bounds__(256) hopb_k(const short* __restrict__ fin,
                                              short* __restrict__ fout,
                                              const int* __restrict__ indptr,
                                              const unsigned* __restrict__ sedge) {
    int node = blockIdx.x * 4 + (threadIdx.x >> 6);
    if (node >= N_NODES) return;
    int l  = threadIdx.x & 63;
    int q4 = l >> 4;    // edge slot 0..3
    int c  = l & 15;    // int4 chunk within 256B row
    int beg = indptr[node], end = indptr[node + 1];
    float acc[8] = {0.f,0.f,0.f,0.f,0.f,0.f,0.f,0.f};
    for (int e = beg + q4; e < end; e += 4) {
        unsigned ed = sedge[e];
        float wt = (float)(ed & 32767u) * (1.f / 32768.f);
        unsigned s = ed >> 15;
        short sv[8];
        *(int4*)sv = *(const int4*)(fin + (size_t)s * 128 + c * 8);
#pragma unroll
        for (int d = 0; d < 8; d++) acc[d] += bf2f(sv[d]) * wt;
    }
#pragma unroll
    for (int d = 0; d < 8; d++) {
        acc[d] += __shfl_xor(acc[d], 16, 64);
        acc[d] += __shfl_xor(acc[d], 32, 64);
    }
    if (q4 == 0) {
        short sv[8];
#pragma unroll
        for (int d = 0; d < 8; d++) sv[d] = f2bf(acc[d]);
        *(int4*)(fout + (size_t)node * 128 + c * 8) = *(int4*)sv;
    }
}

// ---------------- MFMA Gram: Gpart[b] = ftb_chunk^T @ ftb_chunk (384 rows) ----
__global__ void __launch_bounds__(256) gram_k(const short* __restrict__ ftb,
                                              float* __restrict__ Gpart,
                                              float* __restrict__ colsum) {
    __shared__ int  sInt[128 * 17];
    __shared__ float scol[128];
    int tid = threadIdx.x;
    int w   = tid >> 6;
    int l   = tid & 63;
    int q   = l >> 4;
    int r16 = l & 15;
    int i0  = (w >> 1) * 64;
    int j0  = (w & 1) * 64;
    int row0 = blockIdx.x * 384;
    short* sS = (short*)sInt;

    if (tid < 128) scol[tid] = 0.f;

    floatx4 acc[4][4];
#pragma unroll
    for (int a = 0; a < 4; a++)
#pragma unroll
        for (int b = 0; b < 4; b++) acc[a][b] = (floatx4){0.f, 0.f, 0.f, 0.f};
    float colacc[8] = {0.f,0.f,0.f,0.f,0.f,0.f,0.f,0.f};
    int g = tid & 15;

    for (int st = 0; st < 12; st++) {
        __syncthreads();
#pragma unroll
        for (int uu = 0; uu < 2; uu++) {
            int r = (tid >> 4) + uu * 16;
            int gr = row0 + st * 32 + r;
            short v[8];
            if (gr < N_NODES) {
                *(int4*)v = *(const int4*)(ftb + (size_t)gr * 128 + g * 8);
            } else {
#pragma unroll
                for (int d = 0; d < 8; d++) v[d] = 0;
            }
#pragma unroll
            for (int d = 0; d < 8; d++) {
                sS[(g * 8 + d) * 34 + r] = v[d];
                colacc[d] += bf2f(v[d]);
            }
        }
        __syncthreads();
        short8 af[4], bf[4];
#pragma unroll
        for (int ti = 0; ti < 4; ti++) {
            union { int i[4]; short8 s; } u;
            const int* base = &sInt[(i0 + ti * 16 + r16) * 17 + q * 4];
            u.i[0] = base[0]; u.i[1] = base[1]; u.i[2] = base[2]; u.i[3] = base[3];
            af[ti] = u.s;
        }
#pragma unroll
        for (int tj = 0; tj < 4; tj++) {
            union { int i[4]; short8 s; } u;
            const int* base = &sInt[(j0 + tj * 16 + r16) * 17 + q * 4];
            u.i[0] = base[0]; u.i[1] = base[1]; u.i[2] = base[2]; u.i[3] = base[3];
            bf[tj] = u.s;
        }
#pragma unroll
        for (int ti = 0; ti < 4; ti++)
#pragma unroll
            for (int tj = 0; tj < 4; tj++)
                acc[ti][tj] = __builtin_amdgcn_mfma_f32_16x16x32_bf16(af[ti], bf[tj], acc[ti][tj], 0, 0, 0);
    }

    float* gp = Gpart + (size_t)blockIdx.x * 16384;
#pragma unroll
    for (int ti = 0; ti < 4; ti++) {
        int gi = i0 + ti * 16 + q * 4;
#pragma unroll
        for (int tj = 0; tj < 4; tj++) {
            int gj = j0 + tj * 16 + r16;
#pragma unroll
            for (int i2 = 0; i2 < 4; i2++)
                gp[(gi + i2) * 128 + gj] = acc[ti][tj][i2];
        }
    }
    __syncthreads();
#pragma unroll
    for (int d = 0; d < 8; d++) atomicAdd(&scol[g * 8 + d], colacc[d]);
    __syncthreads();
    if (tid < 128) atomicAdd(&colsum[tid], scol[tid]);
}

__global__ void __launch_bounds__(256) reduce_k(const float* __restrict__ Gpart,
                                                float* __restrict__ G) {
    int idx = blockIdx.x * 256 + threadIdx.x;
    float s = 0.f;
    for (int b = 0; b < NB_GRAM; b++) s += Gpart[(size_t)b * 16384 + idx];
    G[idx] = s;
}

// ---------------- BN stats from Gram: one block per hidden unit ----------------
__global__ void __launch_bounds__(128) bnstat_k(const float* __restrict__ G,
                                                const float* __restrict__ colsum,
                                                const float* __restrict__ W1,
                                                const float* __restrict__ b1,
                                                const float* __restrict__ gamma,
                                                const float* __restrict__ beta,
                                                float* __restrict__ scale,
                                                float* __restrict__ shift) {
    __shared__ float sw[128];
    __shared__ float red[4];
    int j = blockIdx.x;
    int l = threadIdx.x;
    float wl = W1[(size_t)j * IN_F + l];
    sw[l] = wl;
    __syncthreads();
    float t = 0.f;
#pragma unroll 8
    for (int k = 0; k < 128; k++) t += sw[k] * G[k * 128 + l];
    float q = wl * t;
    float m = colsum[l] * wl;
#pragma unroll
    for (int off = 32; off >= 1; off >>= 1) {
        q += __shfl_xor(q, off, 64);
        m += __shfl_xor(m, off, 64);
    }
    if ((l & 63) == 0) { red[(l >> 6) * 2] = q; red[(l >> 6) * 2 + 1] = m; }
    __syncthreads();
    if (l == 0) {
        float qq = red[0] + red[2];
        float mm = red[1] + red[3];
        const float invN = 1.f / (float)N_NODES;
        float mean_dot = mm * invN;
        float var = qq * invN - mean_dot * mean_dot;
        float inv = rsqrtf(var + BN_EPS);
        float s = gamma[j] * inv;
        scale[j] = s;
        shift[j] = beta[j] - (mean_dot + b1[j]) * s;
    }
}

// ---------------- weight bf16 pre-conversion ----------------
__global__ void cvtw_k(const float* __restrict__ w1, const float* __restrict__ w2,
                       short* __restrict__ w1b, short* __restrict__ w2b) {
    int i = blockIdx.x * 256 + threadIdx.x;
    if (i < N_HID * IN_F) w1b[i] = f2bf(w1[i]);
    if (i < N_CLS * N_HID) w2b[i] = f2bf(w2[i]);
}

// ---------------- fused fc1 -> BN -> ReLU -> fc2, MFMA ----------------
__global__ void __launch_bounds__(256) mlp_k(const short* __restrict__ ftb,
                                             const short* __restrict__ w1b,
                                             const float* __restrict__ b1,
                                             const float* __restrict__ scale,
                                             const float* __restrict__ shift,
                                             const short* __restrict__ w2b,
                                             const float* __restrict__ b2,
                                             float* __restrict__ out) {
    __shared__ short sA[128][136];
    __shared__ short sW1[64][136];
    __shared__ short sH[128][72];
    __shared__ short sW2[64][72];

    int tid = threadIdx.x;
    int w   = tid >> 6;
    int l   = tid & 63;
    int q   = l >> 4;
    int r16 = l & 15;
    int row0 = blockIdx.x * 128;

    for (int i = tid; i < 128 * 16; i += 256) {
        int r = i >> 4, g = i & 15;
        int gr = row0 + r;
        int4 v = {0, 0, 0, 0};
        if (gr < N_NODES) v = *(const int4*)(ftb + (size_t)gr * 128 + g * 8);
        *(int4*)&sA[r][g * 8] = v;
    }

    floatx4 oacc[2][4];
#pragma unroll
    for (int rt = 0; rt < 2; rt++)
#pragma unroll
        for (int tc = 0; tc < 4; tc++) oacc[rt][tc] = (floatx4){0.f, 0.f, 0.f, 0.f};

    for (int jc = 0; jc < 8; jc++) {
        int j0 = jc * 64;
        __syncthreads();
        for (int i = tid; i < 64 * 16; i += 256) {
            int j = i >> 4, k8 = i & 15;
            *(int4*)&sW1[j][k8 * 8] = *(const int4*)&w1b[(size_t)(j0 + j) * IN_F + k8 * 8];
        }
        for (int i = tid; i < 64 * 8; i += 256) {
            int c = i >> 3, k8 = i & 7;
            *(int4*)&sW2[c][k8 * 8] = *(const int4*)&w2b[(size_t)c * N_HID + j0 + k8 * 8];
        }
        __syncthreads();

        floatx4 hacc[2][4];
#pragma unroll
        for (int rt = 0; rt < 2; rt++)
#pragma unroll
            for (int tn = 0; tn < 4; tn++) hacc[rt][tn] = (floatx4){0.f, 0.f, 0.f, 0.f};
#pragma unroll
        for (int ks = 0; ks < 4; ks++) {
            short8 a0 = *(const short8*)&sA[w * 32 + r16][ks * 32 + q * 8];
            short8 a1 = *(const short8*)&sA[w * 32 + 16 + r16][ks * 32 + q * 8];
#pragma unroll
            for (int tn = 0; tn < 4; tn++) {
                short8 b = *(const short8*)&sW1[tn * 16 + r16][ks * 32 + q * 8];
                hacc[0][tn] = __builtin_amdgcn_mfma_f32_16x16x32_bf16(a0, b, hacc[0][tn], 0, 0, 0);
                hacc[1][tn] = __builtin_amdgcn_mfma_f32_16x16x32_bf16(a1, b, hacc[1][tn], 0, 0, 0);
            }
        }
#pragma unroll
        for (int tn = 0; tn < 4; tn++) {
            int col = j0 + tn * 16 + r16;
            float sc = scale[col], sh = shift[col], bb = b1[col];
#pragma unroll
            for (int rt = 0; rt < 2; rt++)
#pragma unroll
                for (int i = 0; i < 4; i++) {
                    float v = (hacc[rt][tn][i] + bb) * sc + sh;
                    sH[w * 32 + rt * 16 + q * 4 + i][tn * 16 + r16] = f2bf(fmaxf(v, 0.f));
                }
        }
        __syncthreads();
#pragma unroll
        for (int ks = 0; ks < 2; ks++) {
            short8 a0 = *(const short8*)&sH[w * 32 + r16][ks * 32 + q * 8];
            short8 a1 = *(const short8*)&sH[w * 32 + 16 + r16][ks * 32 + q * 8];
#pragma unroll
            for (int tc = 0; tc < 4; tc++) {
                short8 b = *(const short8*)&sW2[tc * 16 + r16][ks * 32 + q * 8];
                oacc[0][tc] = __builtin_amdgcn_mfma_f32_16x16x32_bf16(a0, b, oacc[0][tc], 0, 0, 0);
                oacc[1][tc] = __builtin_amdgcn_mfma_f32_16x16x32_bf16(a1, b, oacc[1][tc], 0, 0, 0);
            }
        }
    }

#pragma unroll
    for (int rt = 0; rt < 2; rt++)
#pragma unroll
        for (int tc = 0; tc < 4; tc++) {
            int col = tc * 16 + r16;
            float bb = b2[col];
#pragma unroll
            for (int i = 0; i < 4; i++) {
                int r = row0 + w * 32 + rt * 16 + q * 4 + i;
                if (r < N_NODES) out[(size_t)r * N_CLS + col] = oacc[rt][tc][i] + bb;
            }
        }
}

extern "C" void kernel_launch(void* const* d_in, const int* in_sizes, int n_in,
                              void* d_out, int out_size, void* d_ws, size_t ws_size,
                              hipStream_t stream) {
    const float* feat  = (const float*)d_in[0];
    const int*   src   = (const int*)d_in[1];
    const int*   dst   = (const int*)d_in[2];
    const float* gnorm = (const float*)d_in[3];
    const float* fc1w  = (const float*)d_in[4];
    const float* fc1b  = (const float*)d_in[5];
    const float* gam   = (const float*)d_in[6];
    const float* bet   = (const float*)d_in[7];
    const float* fc2w  = (const float*)d_in[8];
    const float* fc2b  = (const float*)d_in[9];
    float* out = (float*)d_out;

    char* ws = (char*)d_ws;
    const size_t FTB_BYTES = (size_t)N_NODES * IN_F * 2;   // 25.6 MB
    size_t off = 0;
    short* bufA   = (short*)(ws + off); off += FTB_BYTES;  // featb
    short* bufB   = (short*)(ws + off); off += FTB_BYTES;  // ft1b; ft3b aliases after hop2
    short* bufC   = (short*)(ws + off); off += FTB_BYTES;  // ft2b
    int*   scanout= (int*)(ws + off);   off += 460800;     // scan scratch
    int*   Cmat   = (int*)(ws + off);   off += SCAN_PAD * 4;   // [bucket][block] counts->prefix
    int*   indptr = (int*)(ws + off);   off += 409600;     // node indptr (100,096 entries used)
    size_t ebuf_off = off;
    int2*  ebuf   = (int2*)(ws + off);  off += (size_t)N_EDGES * 8;  // bucket-grouped (intermediate)
    unsigned* epack = (unsigned*)(ws + off); off += (size_t)N_EDGES * 4; // node-sorted packed
    float* G      = (float*)(ws + off); off += 128 * 128 * 4;
    float* colsum = (float*)(ws + off); off += 512;
    float* scale  = (float*)(ws + off); off += 2048;
    float* shift  = (float*)(ws + off); off += 2048;
    short* w1b    = (short*)(ws + off); off += (size_t)N_HID * IN_F * 2;
    short* w2b    = (short*)(ws + off); off += (size_t)N_CLS * N_HID * 2;
    // Gpart aliases ebuf+epack (both dead after hop3; gram runs after hop3).
    // Size check (round-5 lesson — do the arithmetic): NB_GRAM*64KB =
    // 261*65536 = 17,104,896 B  <=  ebuf+epack = 12,800,000+6,400,000 =
    // 19,200,000 B. OK.
    float* Gpart  = (float*)(ws + ebuf_off);
    short* featb  = bufA;
    short* ft1b   = bufB;
    short* ft2b   = bufC;
    short* ft3b   = bufB;               // reuse (ft1b dead after hop2)
    (void)ws_size; (void)in_sizes; (void)n_in; (void)out_size;

    hipMemsetAsync(Cmat, 0, SCAN_PAD * 4, stream);   // zeroes the scan padding tail
    hipMemsetAsync(colsum, 0, 512, stream);

    cvtf_k<<<12500, 256, 0, stream>>>((const float4*)feat, featb);
    cvtw_k<<<(N_HID * IN_F + 255) / 256, 256, 0, stream>>>(fc1w, fc2w, w1b, w2b);

    // atomic-free bucketed CSR build + per-bucket node sort
    binhist_k<<<BIN_BLKS, 256, 0, stream>>>(dst, Cmat);
    scan_k<<<1, 1024, 0, stream>>>(Cmat, scanout);
    bscatter_k<<<BIN_BLKS, 256, 0, stream>>>(src, dst, gnorm, Cmat, ebuf);
    bsort_k<<<NBUCK, 256, 0, stream>>>(ebuf, Cmat, epack, indptr);

    // 3 bf16 propagation hops (gather-per-node — round-8 lesson)
    hopb_k<<<(N_NODES + 3) / 4, 256, 0, stream>>>(featb, ft1b, indptr, epack);
    hopb_k<<<(N_NODES + 3) / 4, 256, 0, stream>>>(ft1b, ft2b, indptr, epack);
    hopb_k<<<(N_NODES + 3) / 4, 256, 0, stream>>>(ft2b, ft3b, indptr, epack);

    // BN stats via MFMA Gram (split-K partials + reduction)
    gram_k<<<NB_GRAM, 256, 0, stream>>>(ft3b, Gpart, colsum);
    reduce_k<<<64, 256, 0, stream>>>(Gpart, G);
    bnstat_k<<<N_HID, 128, 0, stream>>>(G, colsum, fc1w, fc1b, gam, bet, scale, shift);

    // fused MFMA MLP
    mlp_k<<<(N_NODES + 127) / 128, 256, 0, stream>>>(ft3b, w1b, fc1b, scale, shift,
                                                     w2b, fc2b, out);
}